// Round 1
// baseline (9722.947 us; speedup 1.0000x reference)
//
#include <hip/hip_runtime.h>
#include <hip/hip_bf16.h>

// ---------------------------------------------------------------------------
// RSSM scan on MI355X.
// Structure:
//   pack_w_kernel   : fp32 weights -> bf16, pre-packed into MFMA B-fragment order
//   act_proj_kernel : act_proj[a][c] = b_in[c] + emb[a] @ w_in[64:96]
//   scan_kernel     : 64 blocks x 512 thr; block owns 16 batch rows, loops t=0..255
//                     (x=LN/relu, GRU, posterior, z-sample). h/z state in LDS fp32.
//   prior_kernel    : deferred, fully parallel prior head over all (b,t) rows.
// All matmuls: v_mfma_f32_16x16x32_bf16.
// A-frag: lane l elem j <- X[l&15][kt*32 + (l>>4)*8 + j]   (consistent with pack)
// C/D   : reg j -> row 4*(l>>4)+j, col nt*16 + (l&15)      (m89-verified layout)
// ---------------------------------------------------------------------------

#define B_   1024
#define L_   256
#define WD_  128
#define AD_  32
#define DD_  256
#define SD_  64
#define HD_  256
#define NA_  17
#define OUT_ 576

typedef __attribute__((ext_vector_type(8))) short bf16x8;
typedef __attribute__((ext_vector_type(4))) float f32x4;

// packed-weight offsets in d_ws (in bf16/short elements)
#define OFF_WZ   0        // w_in rows 0:64   (64 x 256),  KT=2
#define OFF_WIH  16384    // w_ih            (256 x 768),  KT=8
#define OFF_WHH  212992   // w_hh            (256 x 768),  KT=8
#define OFF_WQ1H 409600   // w_q1 rows 0:256 (256 x 256),  KT=8
#define OFF_WQ1W 475136   // w_q1 rows 256:384(128 x 256), KT=4
#define OFF_WQ2  507904   // w_q2            (256 x 128),  KT=8
#define OFF_WP1  540672   // w_p1            (256 x 256),  KT=8
#define OFF_WP2  606208   // w_p2            (256 x 128),  KT=8
#define PK_TOTAL 638976
#define OFF_ACTP_BYTES (PK_TOTAL * 2)   // float[17*256] after packed weights

__device__ __forceinline__ short f2bf(float f) {
    union { float f; unsigned u; } v; v.f = f;
    unsigned r = (v.u + 0x7fffu + ((v.u >> 16) & 1u)) >> 16;  // RNE
    return (short)r;
}

__device__ __forceinline__ f32x4 mfma16(bf16x8 a, bf16x8 b, f32x4 c) {
    return __builtin_amdgcn_mfma_f32_16x16x32_bf16(a, b, c, 0, 0, 0);
}

__device__ __forceinline__ float sigmoidf_(float x) { return 1.f / (1.f + __expf(-x)); }
__device__ __forceinline__ float tanhf_(float x)    { return 2.f / (1.f + __expf(-2.f * x)) - 1.f; }
__device__ __forceinline__ float softplusf_(float x){ return (x > 20.f) ? x : __logf(1.f + __expf(x)); }

// ---------------------------------------------------------------------------
__global__ void pack_w_kernel(const float* __restrict__ W, short* __restrict__ dst,
                              int KT, int rowOff, int srcN, int total) {
    int tid = blockIdx.x * 256 + threadIdx.x;
    if (tid >= total) return;
    int j    = tid & 7;
    int lane = (tid >> 3) & 63;
    int kt   = (tid >> 9) % KT;
    int nt   = (tid >> 9) / KT;
    int k = kt * 32 + (lane >> 4) * 8 + j;
    int n = nt * 16 + (lane & 15);
    dst[tid] = f2bf(W[(size_t)(rowOff + k) * srcN + n]);
}

__global__ void act_proj_kernel(const float* __restrict__ emb, const float* __restrict__ w_in,
                                const float* __restrict__ b_in, float* __restrict__ actp) {
    int c = threadIdx.x;   // 256
    int a = blockIdx.x;    // 17
    float s = b_in[c];
    for (int i = 0; i < AD_; ++i) s += emb[a * AD_ + i] * w_in[(SD_ + i) * HD_ + c];
    actp[a * HD_ + c] = s;
}

// ---------------------------------------------------------------------------
#define RPB 16
#define NTH 512

__launch_bounds__(NTH, 2)
__global__ void scan_kernel(const int* __restrict__ actions, const float* __restrict__ obs,
                            const float* __restrict__ noise,
                            const float* __restrict__ b_ih, const float* __restrict__ b_hh,
                            const float* __restrict__ g_ln, const float* __restrict__ beta_ln,
                            const float* __restrict__ b_q1, const float* __restrict__ b_q2,
                            const short* __restrict__ wpk, const float* __restrict__ actp,
                            float* __restrict__ out) {
    constexpr int SX = 264;   // bf16 row stride (256 + 8 pad -> conflict-free b128 A-frags)
    constexpr int SZ = 72;
    constexpr int SO = 136;
    constexpr int SF = 265;   // fp32 row stride (odd-ish bank shift)
    constexpr int SQ = 132;

    __shared__ __align__(16) float h_f32[RPB][SF];
    __shared__ __align__(16) float xpre [RPB][SF];
    __shared__ __align__(16) float q2buf[RPB][SQ];
    __shared__ __align__(16) short h_b16 [RPB][SX];
    __shared__ __align__(16) short x_b16 [RPB][SX];
    __shared__ __align__(16) short q1_b16[RPB][SX];
    __shared__ __align__(16) short z_b16 [RPB][SZ];
    __shared__ __align__(16) short obs_b16[RPB][SO];

    const int tid  = threadIdx.x;
    const int wid  = tid >> 6;     // 0..7
    const int lane = tid & 63;
    const int lrow = lane & 15;
    const int lgrp = lane >> 4;
    const int row0 = blockIdx.x * RPB;
    const f32x4 zero4 = {0.f, 0.f, 0.f, 0.f};

    const short* wz   = wpk + OFF_WZ;
    const short* wih  = wpk + OFF_WIH;
    const short* whh  = wpk + OFF_WHH;
    const short* wq1h = wpk + OFF_WQ1H;
    const short* wq1w = wpk + OFF_WQ1W;
    const short* wq2  = wpk + OFF_WQ2;

    for (int i = tid; i < RPB * SX; i += NTH) ((short*)h_b16)[i] = 0;
    for (int i = tid; i < RPB * SF; i += NTH) ((float*)h_f32)[i] = 0.f;
    for (int i = tid; i < RPB * SZ; i += NTH) ((short*)z_b16)[i] = 0;
    __syncthreads();

    for (int t = 0; t < L_; ++t) {
        // ---- Phase A: xpre = z @ Wz + act_proj[action]  (b_in folded in)
        {
            f32x4 acc0 = zero4, acc1 = zero4;
            #pragma unroll
            for (int kt = 0; kt < 2; ++kt) {
                bf16x8 a  = *(const bf16x8*)&z_b16[lrow][kt * 32 + lgrp * 8];
                bf16x8 b0 = *(const bf16x8*)&wz[((2 * wid + 0) * 2 + kt) * 512 + lane * 8];
                bf16x8 b1 = *(const bf16x8*)&wz[((2 * wid + 1) * 2 + kt) * 512 + lane * 8];
                acc0 = mfma16(a, b0, acc0);
                acc1 = mfma16(a, b1, acc1);
            }
            #pragma unroll
            for (int i = 0; i < 2; ++i) {
                f32x4 acc = i ? acc1 : acc0;
                int colb = (2 * wid + i) * 16 + lrow;
                #pragma unroll
                for (int j = 0; j < 4; ++j) {
                    int r = lgrp * 4 + j;
                    int act = actions[(row0 + r) * L_ + t];
                    xpre[r][colb] = acc[j] + actp[act * HD_ + colb];
                }
            }
        }
        // stage obs tile -> bf16 LDS (used in Phase D)
        {
            int r  = tid >> 5;
            int c0 = (tid & 31) * 4;
            float4 v = *(const float4*)&obs[((size_t)(row0 + r) * L_ + t) * WD_ + c0];
            obs_b16[r][c0 + 0] = f2bf(v.x);
            obs_b16[r][c0 + 1] = f2bf(v.y);
            obs_b16[r][c0 + 2] = f2bf(v.z);
            obs_b16[r][c0 + 3] = f2bf(v.w);
        }
        __syncthreads();   // (1)

        // ---- LayerNorm + relu -> x_b16 (32 threads per row)
        {
            int r = tid >> 5, cg = tid & 31;
            float v[8]; float s = 0.f, ss = 0.f;
            #pragma unroll
            for (int k = 0; k < 8; ++k) {
                float x = xpre[r][cg + 32 * k];
                v[k] = x; s += x; ss += x * x;
            }
            #pragma unroll
            for (int d = 1; d < 32; d <<= 1) {
                s  += __shfl_xor(s, d, 64);
                ss += __shfl_xor(ss, d, 64);
            }
            float mean = s * (1.f / 256.f);
            float var  = ss * (1.f / 256.f) - mean * mean;
            float rstd = rsqrtf(var + 1e-5f);
            #pragma unroll
            for (int k = 0; k < 8; ++k) {
                int c = cg + 32 * k;
                float xn = (v[k] - mean) * rstd * g_ln[c] + beta_ln[c];
                x_b16[r][c] = f2bf(fmaxf(xn, 0.f));
            }
        }
        __syncthreads();   // (2)

        // ---- Phase B: gi = x @ w_ih, gh = h @ w_hh (wave owns 32 gate-cols)
        f32x4 aci[3][2], ach[3][2];
        #pragma unroll
        for (int g = 0; g < 3; ++g)
            #pragma unroll
            for (int i = 0; i < 2; ++i) { aci[g][i] = zero4; ach[g][i] = zero4; }
        for (int kt = 0; kt < 8; ++kt) {
            bf16x8 ax = *(const bf16x8*)&x_b16[lrow][kt * 32 + lgrp * 8];
            bf16x8 ah = *(const bf16x8*)&h_b16[lrow][kt * 32 + lgrp * 8];
            #pragma unroll
            for (int g = 0; g < 3; ++g) {
                #pragma unroll
                for (int i = 0; i < 2; ++i) {
                    int nt = 16 * g + 2 * wid + i;
                    bf16x8 bi = *(const bf16x8*)&wih[(nt * 8 + kt) * 512 + lane * 8];
                    aci[g][i] = mfma16(ax, bi, aci[g][i]);
                    bf16x8 bh = *(const bf16x8*)&whh[(nt * 8 + kt) * 512 + lane * 8];
                    ach[g][i] = mfma16(ah, bh, ach[g][i]);
                }
            }
        }
        __syncthreads();   // (3) all reads of h_b16/x_b16 done before h rewrite

        // ---- Phase C: GRU gates, h update, write h to out
        #pragma unroll
        for (int i = 0; i < 2; ++i) {
            #pragma unroll
            for (int j = 0; j < 4; ++j) {
                int colb = (2 * wid + i) * 16 + lrow;
                int r = lgrp * 4 + j;
                float ir  = aci[0][i][j] + b_ih[colb];
                float iu  = aci[1][i][j] + b_ih[256 + colb];
                float in_ = aci[2][i][j] + b_ih[512 + colb];
                float hr  = ach[0][i][j] + b_hh[colb];
                float hu  = ach[1][i][j] + b_hh[256 + colb];
                float hn  = ach[2][i][j] + b_hh[512 + colb];
                float rr = sigmoidf_(ir + hr);
                float uu = sigmoidf_(iu + hu);
                float nn = tanhf_(in_ + rr * hn);
                float ho = h_f32[r][colb];
                float hv = (1.f - uu) * nn + uu * ho;
                h_f32[r][colb] = hv;
                h_b16[r][colb] = f2bf(hv);
                out[((size_t)(row0 + r) * L_ + t) * OUT_ + colb] = hv;
            }
        }
        __syncthreads();   // (4)

        // ---- Phase D: q1 = relu(h_new @ wq1h + obs @ wq1w + b_q1)
        {
            f32x4 acc[2] = {zero4, zero4};
            for (int kt = 0; kt < 8; ++kt) {
                bf16x8 a = *(const bf16x8*)&h_b16[lrow][kt * 32 + lgrp * 8];
                #pragma unroll
                for (int i = 0; i < 2; ++i) {
                    int nt = 2 * wid + i;
                    bf16x8 b = *(const bf16x8*)&wq1h[(nt * 8 + kt) * 512 + lane * 8];
                    acc[i] = mfma16(a, b, acc[i]);
                }
            }
            #pragma unroll
            for (int kt = 0; kt < 4; ++kt) {
                bf16x8 a = *(const bf16x8*)&obs_b16[lrow][kt * 32 + lgrp * 8];
                #pragma unroll
                for (int i = 0; i < 2; ++i) {
                    int nt = 2 * wid + i;
                    bf16x8 b = *(const bf16x8*)&wq1w[(nt * 4 + kt) * 512 + lane * 8];
                    acc[i] = mfma16(a, b, acc[i]);
                }
            }
            #pragma unroll
            for (int i = 0; i < 2; ++i) {
                int colb = (2 * wid + i) * 16 + lrow;
                #pragma unroll
                for (int j = 0; j < 4; ++j) {
                    int r = lgrp * 4 + j;
                    q1_b16[r][colb] = f2bf(fmaxf(acc[i][j] + b_q1[colb], 0.f));
                }
            }
        }
        __syncthreads();   // (5)

        // ---- Phase E: qstats = q1 @ wq2 + b_q2 (wave owns 1 n-tile)
        {
            f32x4 acc = zero4;
            for (int kt = 0; kt < 8; ++kt) {
                bf16x8 a = *(const bf16x8*)&q1_b16[lrow][kt * 32 + lgrp * 8];
                bf16x8 b = *(const bf16x8*)&wq2[(wid * 8 + kt) * 512 + lane * 8];
                acc = mfma16(a, b, acc);
            }
            int colb = wid * 16 + lrow;
            #pragma unroll
            for (int j = 0; j < 4; ++j) {
                int r = lgrp * 4 + j;
                q2buf[r][colb] = acc[j] + b_q2[colb];
            }
        }
        __syncthreads();   // (6)

        // ---- z sample + write z/qm/qs
        {
            int r = tid >> 5, c = tid & 31;
            #pragma unroll
            for (int k = 0; k < 2; ++k) {
                int n = c + 32 * k;
                float qm = q2buf[r][n];
                float qs = softplusf_(q2buf[r][64 + n]) + 0.1f;
                float eps = noise[((size_t)(row0 + r) * L_ + t) * SD_ + n];
                float zv = qm + qs * eps;
                z_b16[r][n] = f2bf(zv);
                size_t ob = ((size_t)(row0 + r) * L_ + t) * OUT_;
                out[ob + 256 + n] = zv;
                out[ob + 448 + n] = qm;
                out[ob + 512 + n] = qs;
            }
        }
        __syncthreads();   // (7)
    }
}

// ---------------------------------------------------------------------------
// Deferred prior head: pstats = relu(h @ w_p1 + b_p1) @ w_p2 + b_p2
// over all (b*L) rows; reads h back from out[...,0:256].
__launch_bounds__(256, 2)
__global__ void prior_kernel(const float* __restrict__ b_p1, const float* __restrict__ b_p2,
                             const short* __restrict__ wpk, float* __restrict__ out) {
    const short* wp1 = wpk + OFF_WP1;
    const short* wp2 = wpk + OFF_WP2;
    __shared__ __align__(16) short p1b[4][16][264];
    const int tid = threadIdx.x, wid = tid >> 6, lane = tid & 63;
    const int lrow = lane & 15, lgrp = lane >> 4;
    const size_t rbase = (size_t)blockIdx.x * 64 + wid * 16;
    const f32x4 zero4 = {0.f, 0.f, 0.f, 0.f};

    f32x4 acc[16];
    #pragma unroll
    for (int nt = 0; nt < 16; ++nt) acc[nt] = zero4;
    for (int kt = 0; kt < 8; ++kt) {
        const float4* hp = (const float4*)&out[(rbase + lrow) * OUT_ + kt * 32 + lgrp * 8];
        float4 h0 = hp[0], h1 = hp[1];
        bf16x8 a;
        a[0] = f2bf(h0.x); a[1] = f2bf(h0.y); a[2] = f2bf(h0.z); a[3] = f2bf(h0.w);
        a[4] = f2bf(h1.x); a[5] = f2bf(h1.y); a[6] = f2bf(h1.z); a[7] = f2bf(h1.w);
        #pragma unroll
        for (int nt = 0; nt < 16; ++nt) {
            bf16x8 b = *(const bf16x8*)&wp1[(nt * 8 + kt) * 512 + lane * 8];
            acc[nt] = mfma16(a, b, acc[nt]);
        }
    }
    #pragma unroll
    for (int nt = 0; nt < 16; ++nt) {
        int colb = nt * 16 + lrow;
        #pragma unroll
        for (int j = 0; j < 4; ++j)
            p1b[wid][lgrp * 4 + j][colb] = f2bf(fmaxf(acc[nt][j] + b_p1[colb], 0.f));
    }
    __syncthreads();

    f32x4 acc2[8];
    #pragma unroll
    for (int nt = 0; nt < 8; ++nt) acc2[nt] = zero4;
    for (int kt = 0; kt < 8; ++kt) {
        bf16x8 a = *(const bf16x8*)&p1b[wid][lrow][kt * 32 + lgrp * 8];
        #pragma unroll
        for (int nt = 0; nt < 8; ++nt) {
            bf16x8 b = *(const bf16x8*)&wp2[(nt * 8 + kt) * 512 + lane * 8];
            acc2[nt] = mfma16(a, b, acc2[nt]);
        }
    }
    #pragma unroll
    for (int nt = 0; nt < 8; ++nt) {
        #pragma unroll
        for (int j = 0; j < 4; ++j) {
            size_t rw = rbase + lgrp * 4 + j;
            int col = nt * 16 + lrow;
            float v = acc2[nt][j] + b_p2[col];
            if (col < 64) out[rw * OUT_ + 320 + col] = v;
            else          out[rw * OUT_ + 384 + (col - 64)] = softplusf_(v) + 0.1f;
        }
    }
}

// ---------------------------------------------------------------------------
extern "C" void kernel_launch(void* const* d_in, const int* in_sizes, int n_in,
                              void* d_out, int out_size, void* d_ws, size_t ws_size,
                              hipStream_t stream) {
    const int*   actions = (const int*)  d_in[0];
    const float* obs     = (const float*)d_in[1];
    const float* noise   = (const float*)d_in[2];
    const float* emb     = (const float*)d_in[3];
    const float* w_in    = (const float*)d_in[4];
    const float* b_in    = (const float*)d_in[5];
    const float* g_ln    = (const float*)d_in[6];
    const float* beta_ln = (const float*)d_in[7];
    const float* w_ih    = (const float*)d_in[8];
    const float* b_ih    = (const float*)d_in[9];
    const float* w_hh    = (const float*)d_in[10];
    const float* b_hh    = (const float*)d_in[11];
    const float* w_p1    = (const float*)d_in[12];
    const float* b_p1    = (const float*)d_in[13];
    const float* w_p2    = (const float*)d_in[14];
    const float* b_p2    = (const float*)d_in[15];
    const float* w_q1    = (const float*)d_in[16];
    const float* b_q1    = (const float*)d_in[17];
    const float* w_q2    = (const float*)d_in[18];
    const float* b_q2    = (const float*)d_in[19];

    short* wpk  = (short*)d_ws;                                  // ~1.3 MB of ws
    float* actp = (float*)((char*)d_ws + OFF_ACTP_BYTES);
    float* out  = (float*)d_out;

    // pack weights (runs every call; deterministic)
    auto packLaunch = [&](const float* W, int off, int KT, int rowOff, int srcN, int total) {
        pack_w_kernel<<<(total + 255) / 256, 256, 0, stream>>>(W, wpk + off, KT, rowOff, srcN, total);
    };
    packLaunch(w_in, OFF_WZ,    2, 0,   256, 64 * 256);
    packLaunch(w_ih, OFF_WIH,   8, 0,   768, 256 * 768);
    packLaunch(w_hh, OFF_WHH,   8, 0,   768, 256 * 768);
    packLaunch(w_q1, OFF_WQ1H,  8, 0,   256, 256 * 256);
    packLaunch(w_q1, OFF_WQ1W,  4, 256, 256, 128 * 256);
    packLaunch(w_q2, OFF_WQ2,   8, 0,   128, 256 * 128);
    packLaunch(w_p1, OFF_WP1,   8, 0,   256, 256 * 256);
    packLaunch(w_p2, OFF_WP2,   8, 0,   128, 256 * 128);
    act_proj_kernel<<<NA_, 256, 0, stream>>>(emb, w_in, b_in, actp);

    scan_kernel<<<B_ / RPB, NTH, 0, stream>>>(actions, obs, noise, b_ih, b_hh,
                                              g_ln, beta_ln, b_q1, b_q2, wpk, actp, out);
    prior_kernel<<<(B_ * L_) / 64, 256, 0, stream>>>(b_p1, b_p2, wpk, out);
}

// Round 2
// 8942.146 us; speedup vs baseline: 1.0873x; 1.0873x over previous
//
#include <hip/hip_runtime.h>
#include <hip/hip_bf16.h>

// ---------------------------------------------------------------------------
// RSSM scan on MI355X — round 2: weights persist in registers.
// scan_kernel: 64 blocks x 1024 thr (16 waves, 4/SIMD). Block owns 16 batch
// rows. Each wave holds its weight B-fragments in VGPRs (loaded once):
//   GRU: nt = {w, 16+w, 32+w}  (gate-aligned -> in-lane gate math)
//   q1 : nt = w ;  q2 : nt = w>>1, k-half = w&1
// MFMA operand-swapped: mfma(W_frag, act_frag) -> D[outcol][batchrow];
// lane = (4 outcols x 1 batchrow); h_old lives in 4 regs/lane across steps.
// Activations circulate via fragment-order LDS buffers (contiguous b128).
// Fragment addr (shorts): F[kt*512 + l*8 + j] = X[row=l&15][k=kt*32+(l>>4)*8+j]
// ---------------------------------------------------------------------------

#define B_   1024
#define L_   256
#define WD_  128
#define AD_  32
#define DD_  256
#define SD_  64
#define HD_  256
#define NA_  17
#define OUT_ 576

typedef __attribute__((ext_vector_type(8))) short bf16x8;
typedef __attribute__((ext_vector_type(4))) float f32x4;

// packed-weight offsets in d_ws (bf16 elements)
#define OFF_WZ   0        // w_in rows 0:64   (64 x 256),  KT=2
#define OFF_WIH  16384    // w_ih            (256 x 768),  KT=8
#define OFF_WHH  212992   // w_hh            (256 x 768),  KT=8
#define OFF_WQ1H 409600   // w_q1 rows 0:256 (256 x 256),  KT=8
#define OFF_WQ1W 475136   // w_q1 rows 256:384(128 x 256), KT=4
#define OFF_WQ2  507904   // w_q2            (256 x 128),  KT=8
#define OFF_WP1  540672   // w_p1            (256 x 256),  KT=8
#define OFF_WP2  606208   // w_p2            (256 x 128),  KT=8
#define PK_TOTAL 638976
#define OFF_ACTP_BYTES (PK_TOTAL * 2)   // float[17*256] after packed weights

__device__ __forceinline__ short f2bf(float f) {
    union { float f; unsigned u; } v; v.f = f;
    unsigned r = (v.u + 0x7fffu + ((v.u >> 16) & 1u)) >> 16;  // RNE
    return (short)r;
}

__device__ __forceinline__ f32x4 mfma16(bf16x8 a, bf16x8 b, f32x4 c) {
    return __builtin_amdgcn_mfma_f32_16x16x32_bf16(a, b, c, 0, 0, 0);
}

__device__ __forceinline__ float sigmoidf_(float x) { return 1.f / (1.f + __expf(-x)); }
__device__ __forceinline__ float tanhf_(float x)    { return 2.f / (1.f + __expf(-2.f * x)) - 1.f; }
__device__ __forceinline__ float softplusf_(float x){ return (x > 20.f) ? x : __logf(1.f + __expf(x)); }

// ---------------------------------------------------------------------------
__global__ void pack_w_kernel(const float* __restrict__ W, short* __restrict__ dst,
                              int KT, int rowOff, int srcN, int total) {
    int tid = blockIdx.x * 256 + threadIdx.x;
    if (tid >= total) return;
    int j    = tid & 7;
    int lane = (tid >> 3) & 63;
    int kt   = (tid >> 9) % KT;
    int nt   = (tid >> 9) / KT;
    int k = kt * 32 + (lane >> 4) * 8 + j;
    int n = nt * 16 + (lane & 15);
    dst[tid] = f2bf(W[(size_t)(rowOff + k) * srcN + n]);
}

__global__ void act_proj_kernel(const float* __restrict__ emb, const float* __restrict__ w_in,
                                const float* __restrict__ b_in, float* __restrict__ actp) {
    int c = threadIdx.x;   // 256
    int a = blockIdx.x;    // 17
    float s = b_in[c];
    for (int i = 0; i < AD_; ++i) s += emb[a * AD_ + i] * w_in[(SD_ + i) * HD_ + c];
    actp[a * HD_ + c] = s;
}

// ---------------------------------------------------------------------------
#define RPB 16
#define NTH 1024

__launch_bounds__(NTH, 4)
__global__ void scan_kernel(const int* __restrict__ actions, const float* __restrict__ obs,
                            const float* __restrict__ noise,
                            const float* __restrict__ b_ih, const float* __restrict__ b_hh,
                            const float* __restrict__ g_ln, const float* __restrict__ beta_ln,
                            const float* __restrict__ b_q1, const float* __restrict__ b_q2,
                            const short* __restrict__ wpk, const float* __restrict__ actp,
                            float* __restrict__ out) {
    __shared__ __align__(16) float xpre[RPB][260];      // fp32 pre-LN, row-major
    __shared__ __align__(16) float q2p[2][RPB][132];    // q2 partials (k-halves)
    __shared__ __align__(16) float mr[RPB][2];          // LN mean, rstd
    __shared__ __align__(16) short xF [8 * 512];        // frag-order activations
    __shared__ __align__(16) short hF [8 * 512];
    __shared__ __align__(16) short q1F[8 * 512];
    __shared__ __align__(16) short zF [2 * 512];
    __shared__ __align__(16) short obsF[4 * 512];

    const int tid  = threadIdx.x;
    const int w    = tid >> 6;          // wave 0..15
    const int lane = tid & 63;
    const int lrow = lane & 15;         // batch row (D-col)
    const int lgrp = lane >> 4;
    const int row0 = blockIdx.x * RPB;
    const int c0   = w * 16 + lgrp * 4; // lane's out-col base (phases A,C,D)
    const int foff = lane * 8;          // frag read offset (shorts)
    // frag WRITE offset: value (row=lrow, k=c0+jj)
    const int fw = (c0 >> 5) * 512 + (lrow + 16 * ((c0 >> 3) & 3)) * 8 + (c0 & 7);
    // LN-write mapping: thread owns frag shorts [tid*4 .. tid*4+3]
    const int ln_l = (tid >> 1) & 63;
    const int ln_r = ln_l & 15;
    const int ln_c = (tid >> 7) * 32 + (ln_l >> 4) * 8 + (tid & 1) * 4;
    const f32x4 zero4 = {0.f, 0.f, 0.f, 0.f};

    // ---- prologue: weights -> registers (once) -------------------------------
    bf16x8 Wz[2], Wih[3][8], Whh[3][8], Wq1h[8], Wq1w[4], Wq2[4];
    {
        const short* wz = wpk + OFF_WZ;
        #pragma unroll
        for (int kt = 0; kt < 2; ++kt)
            Wz[kt] = *(const bf16x8*)&wz[(w * 2 + kt) * 512 + foff];
        const short* wih = wpk + OFF_WIH;
        const short* whh = wpk + OFF_WHH;
        #pragma unroll
        for (int g = 0; g < 3; ++g)
            #pragma unroll
            for (int kt = 0; kt < 8; ++kt) {
                Wih[g][kt] = *(const bf16x8*)&wih[((16 * g + w) * 8 + kt) * 512 + foff];
                Whh[g][kt] = *(const bf16x8*)&whh[((16 * g + w) * 8 + kt) * 512 + foff];
            }
        const short* wq1h = wpk + OFF_WQ1H;
        #pragma unroll
        for (int kt = 0; kt < 8; ++kt)
            Wq1h[kt] = *(const bf16x8*)&wq1h[(w * 8 + kt) * 512 + foff];
        const short* wq1w = wpk + OFF_WQ1W;
        #pragma unroll
        for (int kt = 0; kt < 4; ++kt)
            Wq1w[kt] = *(const bf16x8*)&wq1w[(w * 4 + kt) * 512 + foff];
        const short* wq2 = wpk + OFF_WQ2;
        #pragma unroll
        for (int i = 0; i < 4; ++i)
            Wq2[i] = *(const bf16x8*)&wq2[((w >> 1) * 8 + (w & 1) * 4 + i) * 512 + foff];
    }
    // biases -> per-lane registers
    f32x4 bsum01[2], bihn4, bhhn4, bq1r;
    #pragma unroll
    for (int g = 0; g < 2; ++g) {
        float4 a = *(const float4*)&b_ih[g * 256 + c0];
        float4 b = *(const float4*)&b_hh[g * 256 + c0];
        bsum01[g][0] = a.x + b.x; bsum01[g][1] = a.y + b.y;
        bsum01[g][2] = a.z + b.z; bsum01[g][3] = a.w + b.w;
    }
    { float4 a = *(const float4*)&b_ih[512 + c0]; bihn4[0]=a.x; bihn4[1]=a.y; bihn4[2]=a.z; bihn4[3]=a.w; }
    { float4 a = *(const float4*)&b_hh[512 + c0]; bhhn4[0]=a.x; bhhn4[1]=a.y; bhhn4[2]=a.z; bhhn4[3]=a.w; }
    { float4 a = *(const float4*)&b_q1[c0];       bq1r[0]=a.x; bq1r[1]=a.y; bq1r[2]=a.z; bq1r[3]=a.w; }
    const float bq2m = b_q2[lane], bq2l = b_q2[64 + lane];
    const float4 glnv = *(const float4*)&g_ln[ln_c];
    const float4 blnv = *(const float4*)&beta_ln[ln_c];

    float hreg[4] = {0.f, 0.f, 0.f, 0.f};   // h state: rows lrow, cols c0+jj
    for (int i = tid; i < 2 * 512; i += NTH) zF[i] = 0;
    for (int i = tid; i < 8 * 512; i += NTH) hF[i] = 0;
    __syncthreads();

    for (int t = 0; t < L_; ++t) {
        // ---- Phase A: xpre = z @ Wz + actp[action]; stage obs frag ----------
        {
            f32x4 a = zero4;
            bf16x8 z0 = *(const bf16x8*)&zF[foff];
            bf16x8 z1 = *(const bf16x8*)&zF[512 + foff];
            a = mfma16(Wz[0], z0, a);
            a = mfma16(Wz[1], z1, a);
            int act = actions[(row0 + lrow) * L_ + t];
            float4 ap = *(const float4*)&actp[act * HD_ + c0];
            f32x4 xp; xp[0]=a[0]+ap.x; xp[1]=a[1]+ap.y; xp[2]=a[2]+ap.z; xp[3]=a[3]+ap.w;
            *(f32x4*)&xpre[lrow][c0] = xp;
            // obs: wave w = batch row w; lane covers 2 cols
            int cp = lane * 2;
            float2 ov = *(const float2*)&obs[((size_t)(row0 + w) * L_ + t) * WD_ + cp];
            unsigned pk = (unsigned)(unsigned short)f2bf(ov.x)
                        | ((unsigned)(unsigned short)f2bf(ov.y) << 16);
            *(unsigned*)&obsF[(cp >> 5) * 512 + (w + 16 * ((cp >> 3) & 3)) * 8 + (cp & 7)] = pk;
        }
        __syncthreads();   // (1)

        // ---- LN reduce: wave w handles row w --------------------------------
        {
            f32x4 v = *(const f32x4*)&xpre[w][lane * 4];
            float s  = v[0] + v[1] + v[2] + v[3];
            float ss = v[0]*v[0] + v[1]*v[1] + v[2]*v[2] + v[3]*v[3];
            #pragma unroll
            for (int d = 1; d < 64; d <<= 1) {
                s  += __shfl_xor(s, d, 64);
                ss += __shfl_xor(ss, d, 64);
            }
            if (lane == 0) {
                float mean = s * (1.f / 256.f);
                float var  = ss * (1.f / 256.f) - mean * mean;
                mr[w][0] = mean;
                mr[w][1] = rsqrtf(var + 1e-5f);
            }
        }
        __syncthreads();   // (2)

        // ---- LN write: thread owns frag slot tid*4 --------------------------
        {
            float4 xv = *(const float4*)&xpre[ln_r][ln_c];
            float mean = mr[ln_r][0], rstd = mr[ln_r][1];
            short4 xb;
            xb.x = f2bf(fmaxf((xv.x - mean) * rstd * glnv.x + blnv.x, 0.f));
            xb.y = f2bf(fmaxf((xv.y - mean) * rstd * glnv.y + blnv.y, 0.f));
            xb.z = f2bf(fmaxf((xv.z - mean) * rstd * glnv.z + blnv.z, 0.f));
            xb.w = f2bf(fmaxf((xv.w - mean) * rstd * glnv.w + blnv.w, 0.f));
            *(short4*)&xF[tid * 4] = xb;
        }
        __syncthreads();   // (3)

        // ---- Phase B: gi^T, gh^T (weights from regs) ------------------------
        f32x4 ai[3] = {zero4, zero4, zero4}, ah[3] = {zero4, zero4, zero4};
        #pragma unroll
        for (int kt = 0; kt < 8; ++kt) {
            bf16x8 xf = *(const bf16x8*)&xF[kt * 512 + foff];
            bf16x8 hf = *(const bf16x8*)&hF[kt * 512 + foff];
            #pragma unroll
            for (int g = 0; g < 3; ++g) {
                ai[g] = mfma16(Wih[g][kt], xf, ai[g]);
                ah[g] = mfma16(Whh[g][kt], hf, ah[g]);
            }
        }
        __syncthreads();   // (4) all hF reads done before rewrite

        // ---- Phase C: gates, h update ---------------------------------------
        {
            f32x4 hv4;
            #pragma unroll
            for (int jj = 0; jj < 4; ++jj) {
                float rr = sigmoidf_(ai[0][jj] + ah[0][jj] + bsum01[0][jj]);
                float uu = sigmoidf_(ai[1][jj] + ah[1][jj] + bsum01[1][jj]);
                float nn = tanhf_(ai[2][jj] + bihn4[jj] + rr * (ah[2][jj] + bhhn4[jj]));
                float hv = (1.f - uu) * nn + uu * hreg[jj];
                hreg[jj] = hv;
                hv4[jj]  = hv;
            }
            short4 hb;
            hb.x = f2bf(hv4[0]); hb.y = f2bf(hv4[1]);
            hb.z = f2bf(hv4[2]); hb.w = f2bf(hv4[3]);
            *(short4*)&hF[fw] = hb;
            float4 ho; ho.x = hv4[0]; ho.y = hv4[1]; ho.z = hv4[2]; ho.w = hv4[3];
            *(float4*)&out[((size_t)(row0 + lrow) * L_ + t) * OUT_ + c0] = ho;
        }
        __syncthreads();   // (5)

        // ---- Phase D: q1 = relu(h@Wq1h + obs@Wq1w + b_q1) --------------------
        {
            f32x4 a = zero4;
            #pragma unroll
            for (int kt = 0; kt < 8; ++kt)
                a = mfma16(Wq1h[kt], *(const bf16x8*)&hF[kt * 512 + foff], a);
            #pragma unroll
            for (int kt = 0; kt < 4; ++kt)
                a = mfma16(Wq1w[kt], *(const bf16x8*)&obsF[kt * 512 + foff], a);
            short4 qb;
            qb.x = f2bf(fmaxf(a[0] + bq1r[0], 0.f));
            qb.y = f2bf(fmaxf(a[1] + bq1r[1], 0.f));
            qb.z = f2bf(fmaxf(a[2] + bq1r[2], 0.f));
            qb.w = f2bf(fmaxf(a[3] + bq1r[3], 0.f));
            *(short4*)&q1F[fw] = qb;
        }
        __syncthreads();   // (6)

        // ---- Phase E: q2 partials (nt=w>>1, k-half=w&1) ----------------------
        {
            f32x4 a = zero4;
            #pragma unroll
            for (int i = 0; i < 4; ++i)
                a = mfma16(Wq2[i], *(const bf16x8*)&q1F[((w & 1) * 4 + i) * 512 + foff], a);
            *(f32x4*)&q2p[w & 1][lrow][(w >> 1) * 16 + lgrp * 4] = a;
        }
        __syncthreads();   // (7)

        // ---- Phase F: z sample; write z/qm/qs; zF for next step --------------
        {
            int n = lane;
            float qm = q2p[0][w][n]      + q2p[1][w][n]      + bq2m;
            float ql = q2p[0][w][64 + n] + q2p[1][w][64 + n] + bq2l;
            float qs = softplusf_(ql) + 0.1f;
            float eps = noise[((size_t)(row0 + w) * L_ + t) * SD_ + n];
            float zv = qm + qs * eps;
            zF[(n >> 5) * 512 + (w + 16 * ((n >> 3) & 3)) * 8 + (n & 7)] = f2bf(zv);
            size_t ob = ((size_t)(row0 + w) * L_ + t) * OUT_;
            out[ob + 256 + n] = zv;
            out[ob + 448 + n] = qm;
            out[ob + 512 + n] = qs;
        }
        __syncthreads();   // (8)
    }
}

// ---------------------------------------------------------------------------
// Deferred prior head: pstats = relu(h @ w_p1 + b_p1) @ w_p2 + b_p2
__launch_bounds__(256, 2)
__global__ void prior_kernel(const float* __restrict__ b_p1, const float* __restrict__ b_p2,
                             const short* __restrict__ wpk, float* __restrict__ out) {
    const short* wp1 = wpk + OFF_WP1;
    const short* wp2 = wpk + OFF_WP2;
    __shared__ __align__(16) short p1b[4][16][264];
    const int tid = threadIdx.x, wid = tid >> 6, lane = tid & 63;
    const int lrow = lane & 15, lgrp = lane >> 4;
    const size_t rbase = (size_t)blockIdx.x * 64 + wid * 16;
    const f32x4 zero4 = {0.f, 0.f, 0.f, 0.f};

    f32x4 acc[16];
    #pragma unroll
    for (int nt = 0; nt < 16; ++nt) acc[nt] = zero4;
    for (int kt = 0; kt < 8; ++kt) {
        const float4* hp = (const float4*)&out[(rbase + lrow) * OUT_ + kt * 32 + lgrp * 8];
        float4 h0 = hp[0], h1 = hp[1];
        bf16x8 a;
        a[0] = f2bf(h0.x); a[1] = f2bf(h0.y); a[2] = f2bf(h0.z); a[3] = f2bf(h0.w);
        a[4] = f2bf(h1.x); a[5] = f2bf(h1.y); a[6] = f2bf(h1.z); a[7] = f2bf(h1.w);
        #pragma unroll
        for (int nt = 0; nt < 16; ++nt) {
            bf16x8 b = *(const bf16x8*)&wp1[(nt * 8 + kt) * 512 + lane * 8];
            acc[nt] = mfma16(a, b, acc[nt]);
        }
    }
    #pragma unroll
    for (int nt = 0; nt < 16; ++nt) {
        int colb = nt * 16 + lrow;
        #pragma unroll
        for (int j = 0; j < 4; ++j)
            p1b[wid][lgrp * 4 + j][colb] = f2bf(fmaxf(acc[nt][j] + b_p1[colb], 0.f));
    }
    __syncthreads();

    f32x4 acc2[8];
    #pragma unroll
    for (int nt = 0; nt < 8; ++nt) acc2[nt] = zero4;
    for (int kt = 0; kt < 8; ++kt) {
        bf16x8 a = *(const bf16x8*)&p1b[wid][lrow][kt * 32 + lgrp * 8];
        #pragma unroll
        for (int nt = 0; nt < 8; ++nt) {
            bf16x8 b = *(const bf16x8*)&wp2[(nt * 8 + kt) * 512 + lane * 8];
            acc2[nt] = mfma16(a, b, acc2[nt]);
        }
    }
    #pragma unroll
    for (int nt = 0; nt < 8; ++nt) {
        #pragma unroll
        for (int j = 0; j < 4; ++j) {
            size_t rw = rbase + lgrp * 4 + j;
            int col = nt * 16 + lrow;
            float v = acc2[nt][j] + b_p2[col];
            if (col < 64) out[rw * OUT_ + 320 + col] = v;
            else          out[rw * OUT_ + 384 + (col - 64)] = softplusf_(v) + 0.1f;
        }
    }
}

// ---------------------------------------------------------------------------
extern "C" void kernel_launch(void* const* d_in, const int* in_sizes, int n_in,
                              void* d_out, int out_size, void* d_ws, size_t ws_size,
                              hipStream_t stream) {
    const int*   actions = (const int*)  d_in[0];
    const float* obs     = (const float*)d_in[1];
    const float* noise   = (const float*)d_in[2];
    const float* emb     = (const float*)d_in[3];
    const float* w_in    = (const float*)d_in[4];
    const float* b_in    = (const float*)d_in[5];
    const float* g_ln    = (const float*)d_in[6];
    const float* beta_ln = (const float*)d_in[7];
    const float* w_ih    = (const float*)d_in[8];
    const float* b_ih    = (const float*)d_in[9];
    const float* w_hh    = (const float*)d_in[10];
    const float* b_hh    = (const float*)d_in[11];
    const float* w_p1    = (const float*)d_in[12];
    const float* b_p1    = (const float*)d_in[13];
    const float* w_p2    = (const float*)d_in[14];
    const float* b_p2    = (const float*)d_in[15];
    const float* w_q1    = (const float*)d_in[16];
    const float* b_q1    = (const float*)d_in[17];
    const float* w_q2    = (const float*)d_in[18];
    const float* b_q2    = (const float*)d_in[19];

    short* wpk  = (short*)d_ws;
    float* actp = (float*)((char*)d_ws + OFF_ACTP_BYTES);
    float* out  = (float*)d_out;

    auto packLaunch = [&](const float* W, int off, int KT, int rowOff, int srcN, int total) {
        pack_w_kernel<<<(total + 255) / 256, 256, 0, stream>>>(W, wpk + off, KT, rowOff, srcN, total);
    };
    packLaunch(w_in, OFF_WZ,    2, 0,   256, 64 * 256);
    packLaunch(w_ih, OFF_WIH,   8, 0,   768, 256 * 768);
    packLaunch(w_hh, OFF_WHH,   8, 0,   768, 256 * 768);
    packLaunch(w_q1, OFF_WQ1H,  8, 0,   256, 256 * 256);
    packLaunch(w_q1, OFF_WQ1W,  4, 256, 256, 128 * 256);
    packLaunch(w_q2, OFF_WQ2,   8, 0,   128, 256 * 128);
    packLaunch(w_p1, OFF_WP1,   8, 0,   256, 256 * 256);
    packLaunch(w_p2, OFF_WP2,   8, 0,   128, 256 * 128);
    act_proj_kernel<<<NA_, 256, 0, stream>>>(emb, w_in, b_in, actp);

    scan_kernel<<<B_ / RPB, NTH, 0, stream>>>(actions, obs, noise, b_ih, b_hh,
                                              g_ln, beta_ln, b_q1, b_q2, wpk, actp, out);
    prior_kernel<<<(B_ * L_) / 64, 256, 0, stream>>>(b_p1, b_p2, wpk, out);
}